// Round 1
// baseline (490.339 us; speedup 1.0000x reference)
//
#include <hip/hip_runtime.h>
#include <hip/hip_bf16.h>

#define NODES_HINT 100000

// ---------------- zero init (deg floats + cnt ints) ----------------
__global__ void k_zero(float* deg, int* cnt, int n) {
    int i = blockIdx.x * 256 + threadIdx.x;
    if (i < n) { deg[i] = 0.f; cnt[i] = 0; }
}

// ---------------- degree + per-col edge count ----------------
__global__ void k_deg_cnt(const int* col, const float* w, float* deg, int* cnt, int E) {
    int e = blockIdx.x * 256 + threadIdx.x;
    if (e < E) {
        int c = col[e];
        atomicAdd(&deg[c], w[e]);
        atomicAdd(&cnt[c], 1);
    }
}

// ---------------- dinv = rsqrt(deg + 1) (self-loop weight 1) ----------------
__global__ void k_dinv(float* deg, int n) {
    int i = blockIdx.x * 256 + threadIdx.x;
    if (i < n) deg[i] = rsqrtf(deg[i] + 1.0f);   // deg+1 >= 1 > 0 always
}

// ---------------- 3-phase exclusive scan of cnt -> off ----------------
__global__ __launch_bounds__(1024) void k_scan1(const int* cnt, int* excl, int* partials, int n) {
    __shared__ int sm[1024];
    int gid = blockIdx.x * 1024 + threadIdx.x;
    int v = (gid < n) ? cnt[gid] : 0;
    sm[threadIdx.x] = v;
    __syncthreads();
    for (int off = 1; off < 1024; off <<= 1) {
        int t = (threadIdx.x >= off) ? sm[threadIdx.x - off] : 0;
        __syncthreads();
        sm[threadIdx.x] += t;
        __syncthreads();
    }
    if (gid < n) excl[gid] = sm[threadIdx.x] - v;          // exclusive
    if (threadIdx.x == 1023) partials[blockIdx.x] = sm[1023]; // block total
}

__global__ void k_scan2(int* partials, int nb) {
    __shared__ int sm[128];
    int v = (threadIdx.x < nb) ? partials[threadIdx.x] : 0;
    sm[threadIdx.x] = v;
    __syncthreads();
    for (int off = 1; off < 128; off <<= 1) {
        int t = (threadIdx.x >= off) ? sm[threadIdx.x - off] : 0;
        __syncthreads();
        sm[threadIdx.x] += t;
        __syncthreads();
    }
    if (threadIdx.x < nb) partials[threadIdx.x] = sm[threadIdx.x] - v; // exclusive
}

__global__ void k_scan3(int* excl, const int* partials, int* cur, int n, int total) {
    int gid = blockIdx.x * 256 + threadIdx.x;
    if (gid < n) {
        int v = excl[gid] + partials[gid >> 10];
        excl[gid] = v;
        cur[gid]  = v;          // cursor copy for the fill pass
    } else if (gid == n) {
        excl[n] = total;
    }
}

// ---------------- CSR fill: slot = cur[col]++, record src + norm ----------------
__global__ void k_fill(const int* row, const int* col, const float* w, const float* dinv,
                       int* cur, int* esrc, float* enorm, int E) {
    int e = blockIdx.x * 256 + threadIdx.x;
    if (e < E) {
        int r = row[e], c = col[e];
        int slot = atomicAdd(&cur[c], 1);
        esrc[slot]  = r;
        enorm[slot] = dinv[r] * w[e] * dinv[c];
    }
}

// ---------------- h1 = x @ W1  (wave per node, W1 in LDS) ----------------
__global__ void k_gemm1(const float* __restrict__ x, const float* __restrict__ W1,
                        float* __restrict__ h1, int n) {
    __shared__ float Ws[64 * 64];
    for (int t = threadIdx.x; t < 4096; t += 256) Ws[t] = W1[t];
    __syncthreads();
    int lane = threadIdx.x & 63;
    int wave = threadIdx.x >> 6;
    for (int i = blockIdx.x * 4 + wave; i < n; i += gridDim.x * 4) {
        float xv = x[(size_t)i * 64 + lane];
        float acc = 0.f;
#pragma unroll
        for (int k = 0; k < 64; ++k) {
            float xk = __shfl(xv, k, 64);
            acc = fmaf(xk, Ws[k * 64 + lane], acc);
        }
        h1[(size_t)i * 64 + lane] = acc;
    }
}

// ---------------- agg1 fused: gather-sum + b1 + relu + dot(W2) -> h2[N] ----------------
__global__ void k_agg1(const float* __restrict__ h1, const int* __restrict__ off,
                       const int* __restrict__ esrc, const float* __restrict__ enorm,
                       const float* __restrict__ dinv, const float* __restrict__ b1,
                       const float* __restrict__ W2, float* __restrict__ h2, int n) {
    int lane = threadIdx.x & 63;
    int wave = threadIdx.x >> 6;
    int i = blockIdx.x * 4 + wave;     // wave-uniform node index
    if (i >= n) return;
    float di = dinv[i];
    float acc = h1[(size_t)i * 64 + lane] * (di * di);   // self-loop
    int s0 = off[i], s1 = off[i + 1];
    for (int s = s0; s < s1; ++s) {
        int src = esrc[s];
        float nm = enorm[s];
        acc = fmaf(h1[(size_t)src * 64 + lane], nm, acc);
    }
    float v = fmaxf(acc + b1[lane], 0.f);
    float p = v * W2[lane];
#pragma unroll
    for (int o = 32; o > 0; o >>= 1) p += __shfl_down(p, o, 64);
    if (lane == 0) h2[i] = p;
}

// ---------------- agg2 on scalars + b2 -> out[N] ----------------
__global__ void k_agg2(const float* __restrict__ h2, const int* __restrict__ off,
                       const int* __restrict__ esrc, const float* __restrict__ enorm,
                       const float* __restrict__ dinv, const float* __restrict__ b2,
                       float* __restrict__ out, int n) {
    int i = blockIdx.x * 256 + threadIdx.x;
    if (i >= n) return;
    float di = dinv[i];
    float acc = h2[i] * di * di;       // self-loop
    int s1 = off[i + 1];
    for (int s = off[i]; s < s1; ++s)
        acc = fmaf(h2[esrc[s]], enorm[s], acc);
    out[i] = acc + b2[0];
}

extern "C" void kernel_launch(void* const* d_in, const int* in_sizes, int n_in,
                              void* d_out, int out_size, void* d_ws, size_t ws_size,
                              hipStream_t stream) {
    const float* x  = (const float*)d_in[0];
    const int*   ei = (const int*)d_in[1];
    const float* w  = (const float*)d_in[2];
    const float* W1 = (const float*)d_in[3];
    const float* b1 = (const float*)d_in[4];
    const float* W2 = (const float*)d_in[5];
    const float* b2 = (const float*)d_in[6];
    float* out = (float*)d_out;

    const int N = in_sizes[0] / 64;
    const int E = in_sizes[2];
    const int* row = ei;
    const int* col = ei + E;

    // workspace carve-up (all 4-byte aligned; ~38 MB total)
    char* p = (char*)d_ws;
    float* deg   = (float*)p; p += (size_t)N * 4;        // becomes dinv in-place
    int*   off   = (int*)p;   p += (size_t)(N + 1) * 4;
    int*   cur   = (int*)p;   p += (size_t)N * 4;
    int*   cnt   = (int*)p;   p += (size_t)N * 4;
    int*   parts = (int*)p;   p += 1024;
    int*   esrc  = (int*)p;   p += (size_t)E * 4;
    float* enorm = (float*)p; p += (size_t)E * 4;
    float* h1    = (float*)p; p += (size_t)N * 64 * 4;
    float* h2    = (float*)p; p += (size_t)N * 4;

    const int gN   = (N + 255) / 256;
    const int gE   = (E + 255) / 256;
    const int nb1  = (N + 1023) / 1024;                  // scan1 blocks (=98)
    const int gN1  = (N + 1 + 255) / 256;                // covers element N too

    k_zero<<<gN, 256, 0, stream>>>(deg, cnt, N);
    k_deg_cnt<<<gE, 256, 0, stream>>>(col, w, deg, cnt, E);
    k_dinv<<<gN, 256, 0, stream>>>(deg, N);
    k_scan1<<<nb1, 1024, 0, stream>>>(cnt, off, parts, N);
    k_scan2<<<1, 128, 0, stream>>>(parts, nb1);
    k_scan3<<<gN1, 256, 0, stream>>>(off, parts, cur, N, E);
    k_fill<<<gE, 256, 0, stream>>>(row, col, w, deg, cur, esrc, enorm, E);
    k_gemm1<<<1024, 256, 0, stream>>>(x, W1, h1, N);
    k_agg1<<<(N + 3) / 4, 256, 0, stream>>>(h1, off, esrc, enorm, deg, b1, W2, h2, N);
    k_agg2<<<gN, 256, 0, stream>>>(h2, off, esrc, enorm, deg, b2, out, N);
}

// Round 2
// 419.197 us; speedup vs baseline: 1.1697x; 1.1697x over previous
//
#include <hip/hip_runtime.h>
#include <hip/hip_bf16.h>

// ---------------- zero init: interleaved degcnt (2N ints) ----------------
__global__ void k_zero(int* degcnt, int n2) {
    int i = blockIdx.x * 256 + threadIdx.x;
    if (i < n2) degcnt[i] = 0;
}

// ---------------- degree (float @2c) + count (int @2c+1): same cache line ----------------
__global__ void k_deg_cnt(const int* __restrict__ col, const float* __restrict__ w,
                          int* __restrict__ degcnt, int E) {
    int e = blockIdx.x * 256 + threadIdx.x;
    if (e < E) {
        int c = col[e];
        atomicAdd((float*)&degcnt[2 * c], w[e]);
        atomicAdd(&degcnt[2 * c + 1], 1);
    }
}

// ---------------- dinv[i] = rsqrt(deg + 1) ----------------
__global__ void k_dinv(const int* __restrict__ degcnt, float* __restrict__ dinv, int n) {
    int i = blockIdx.x * 256 + threadIdx.x;
    if (i < n) dinv[i] = rsqrtf(__int_as_float(degcnt[2 * i]) + 1.0f);
}

// ---------------- 3-phase exclusive scan of cnt -> off ----------------
__global__ __launch_bounds__(1024) void k_scan1(const int* __restrict__ degcnt,
                                                int* excl, int* partials, int n) {
    __shared__ int sm[1024];
    int gid = blockIdx.x * 1024 + threadIdx.x;
    int v = (gid < n) ? degcnt[2 * gid + 1] : 0;
    sm[threadIdx.x] = v;
    __syncthreads();
    for (int off = 1; off < 1024; off <<= 1) {
        int t = (threadIdx.x >= off) ? sm[threadIdx.x - off] : 0;
        __syncthreads();
        sm[threadIdx.x] += t;
        __syncthreads();
    }
    if (gid < n) excl[gid] = sm[threadIdx.x] - v;
    if (threadIdx.x == 1023) partials[blockIdx.x] = sm[1023];
}

__global__ void k_scan2(int* partials, int nb) {
    __shared__ int sm[128];
    int v = (threadIdx.x < nb) ? partials[threadIdx.x] : 0;
    sm[threadIdx.x] = v;
    __syncthreads();
    for (int off = 1; off < 128; off <<= 1) {
        int t = (threadIdx.x >= off) ? sm[threadIdx.x - off] : 0;
        __syncthreads();
        sm[threadIdx.x] += t;
        __syncthreads();
    }
    if (threadIdx.x < nb) partials[threadIdx.x] = sm[threadIdx.x] - v;
}

__global__ void k_scan3(int* excl, const int* partials, int* cur, int n, int total) {
    int gid = blockIdx.x * 256 + threadIdx.x;
    if (gid < n) {
        int v = excl[gid] + partials[gid >> 10];
        excl[gid] = v;
        cur[gid]  = v;
    } else if (gid == n) {
        excl[n] = total;
    }
}

// ---------------- CSR fill: one packed 8B store per edge ----------------
__global__ void k_fill(const int* __restrict__ row, const int* __restrict__ col,
                       const float* __restrict__ w, const float* __restrict__ dinv,
                       int* __restrict__ cur, float2* __restrict__ ep, int E) {
    int e = blockIdx.x * 256 + threadIdx.x;
    if (e < E) {
        int r = row[e], c = col[e];
        int slot = atomicAdd(&cur[c], 1);
        float nm = dinv[r] * w[e] * dinv[c];
        ep[slot] = make_float2(__int_as_float(r), nm);
    }
}

// ---------------- h1 = x @ W1  (wave per node, W1 in LDS) ----------------
__global__ void k_gemm1(const float* __restrict__ x, const float* __restrict__ W1,
                        float* __restrict__ h1, int n) {
    __shared__ float Ws[64 * 64];
    for (int t = threadIdx.x; t < 4096; t += 256) Ws[t] = W1[t];
    __syncthreads();
    int lane = threadIdx.x & 63;
    int wave = threadIdx.x >> 6;
    for (int i = blockIdx.x * 4 + wave; i < n; i += gridDim.x * 4) {
        float xv = x[(size_t)i * 64 + lane];
        float acc = 0.f;
#pragma unroll
        for (int k = 0; k < 64; ++k) {
            float xk = __shfl(xv, k, 64);
            acc = fmaf(xk, Ws[k * 64 + lane], acc);
        }
        h1[(size_t)i * 64 + lane] = acc;
    }
}

// ---- agg1 fused: gather-sum (4-way unrolled) + b1 + relu + dot(W2) -> h2[N] ----
__global__ void k_agg1(const float* __restrict__ h1, const int* __restrict__ off,
                       const float2* __restrict__ ep, const float* __restrict__ dinv,
                       const float* __restrict__ b1, const float* __restrict__ W2,
                       float* __restrict__ h2, int n) {
    int lane = threadIdx.x & 63;
    int wave = threadIdx.x >> 6;
    int i = blockIdx.x * 4 + wave;
    if (i >= n) return;
    float di = dinv[i];
    float acc = h1[(size_t)i * 64 + lane] * (di * di);   // self-loop
    int s0 = off[i], s1 = off[i + 1];
    int s = s0;
    // 4 independent 256B gathers in flight per iteration
    for (; s + 4 <= s1; s += 4) {
        float2 e0 = ep[s], e1 = ep[s + 1], e2 = ep[s + 2], e3 = ep[s + 3];
        float v0 = h1[(size_t)__float_as_int(e0.x) * 64 + lane];
        float v1 = h1[(size_t)__float_as_int(e1.x) * 64 + lane];
        float v2 = h1[(size_t)__float_as_int(e2.x) * 64 + lane];
        float v3 = h1[(size_t)__float_as_int(e3.x) * 64 + lane];
        acc = fmaf(v0, e0.y, acc);
        acc = fmaf(v1, e1.y, acc);
        acc = fmaf(v2, e2.y, acc);
        acc = fmaf(v3, e3.y, acc);
    }
    for (; s < s1; ++s) {
        float2 e = ep[s];
        acc = fmaf(h1[(size_t)__float_as_int(e.x) * 64 + lane], e.y, acc);
    }
    float v = fmaxf(acc + b1[lane], 0.f);
    float p = v * W2[lane];
#pragma unroll
    for (int o = 32; o > 0; o >>= 1) p += __shfl_down(p, o, 64);
    if (lane == 0) h2[i] = p;
}

// ---------------- agg2 on scalars (4-way unrolled) + b2 -> out[N] ----------------
__global__ void k_agg2(const float* __restrict__ h2, const int* __restrict__ off,
                       const float2* __restrict__ ep, const float* __restrict__ dinv,
                       const float* __restrict__ b2, float* __restrict__ out, int n) {
    int i = blockIdx.x * 256 + threadIdx.x;
    if (i >= n) return;
    float di = dinv[i];
    float acc = h2[i] * di * di;       // self-loop
    int s0 = off[i], s1 = off[i + 1];
    int s = s0;
    for (; s + 4 <= s1; s += 4) {
        float2 e0 = ep[s], e1 = ep[s + 1], e2 = ep[s + 2], e3 = ep[s + 3];
        float v0 = h2[__float_as_int(e0.x)];
        float v1 = h2[__float_as_int(e1.x)];
        float v2 = h2[__float_as_int(e2.x)];
        float v3 = h2[__float_as_int(e3.x)];
        acc = fmaf(v0, e0.y, acc);
        acc = fmaf(v1, e1.y, acc);
        acc = fmaf(v2, e2.y, acc);
        acc = fmaf(v3, e3.y, acc);
    }
    for (; s < s1; ++s) {
        float2 e = ep[s];
        acc = fmaf(h2[__float_as_int(e.x)], e.y, acc);
    }
    out[i] = acc + b2[0];
}

extern "C" void kernel_launch(void* const* d_in, const int* in_sizes, int n_in,
                              void* d_out, int out_size, void* d_ws, size_t ws_size,
                              hipStream_t stream) {
    const float* x  = (const float*)d_in[0];
    const int*   ei = (const int*)d_in[1];
    const float* w  = (const float*)d_in[2];
    const float* W1 = (const float*)d_in[3];
    const float* b1 = (const float*)d_in[4];
    const float* W2 = (const float*)d_in[5];
    const float* b2 = (const float*)d_in[6];
    float* out = (float*)d_out;

    const int N = in_sizes[0] / 64;
    const int E = in_sizes[2];
    const int* row = ei;
    const int* col = ei + E;

    // workspace carve-up (~37 MB)
    char* p = (char*)d_ws;
    int*    degcnt = (int*)p;    p += (size_t)2 * N * 4;   // [2i]=deg(f32), [2i+1]=cnt
    float*  dinv   = (float*)p;  p += (size_t)N * 4;
    int*    off    = (int*)p;    p += (size_t)(N + 1) * 4;
    int*    cur    = (int*)p;    p += (size_t)N * 4;
    int*    parts  = (int*)p;    p += 1024;
    float2* ep     = (float2*)p; p += (size_t)E * 8;       // packed (src, norm)
    float*  h1     = (float*)p;  p += (size_t)N * 64 * 4;
    float*  h2     = (float*)p;  p += (size_t)N * 4;

    const int gN  = (N + 255) / 256;
    const int gE  = (E + 255) / 256;
    const int nb1 = (N + 1023) / 1024;
    const int gN1 = (N + 1 + 255) / 256;

    k_zero<<<(2 * N + 255) / 256, 256, 0, stream>>>(degcnt, 2 * N);
    k_deg_cnt<<<gE, 256, 0, stream>>>(col, w, degcnt, E);
    k_dinv<<<gN, 256, 0, stream>>>(degcnt, dinv, N);
    k_scan1<<<nb1, 1024, 0, stream>>>(degcnt, off, parts, N);
    k_scan2<<<1, 128, 0, stream>>>(parts, nb1);
    k_scan3<<<gN1, 256, 0, stream>>>(off, parts, cur, N, E);
    k_fill<<<gE, 256, 0, stream>>>(row, col, w, dinv, cur, ep, E);
    k_gemm1<<<1024, 256, 0, stream>>>(x, W1, h1, N);
    k_agg1<<<(N + 3) / 4, 256, 0, stream>>>(h1, off, ep, dinv, b1, W2, h2, N);
    k_agg2<<<gN, 256, 0, stream>>>(h2, off, ep, dinv, b2, out, N);
}

// Round 4
// 387.776 us; speedup vs baseline: 1.2645x; 1.0810x over previous
//
#include <hip/hip_runtime.h>
#include <hip/hip_bf16.h>

// degcnt[i] packed u64: high 20 bits = count, low 44 bits = sum(w)*2^32 fixed point
#define DEG_SHIFT 44
#define DEG_MASK  ((1ULL << DEG_SHIFT) - 1)
#define DEG_SCALE 4294967296.0f   // 2^32

__device__ __forceinline__ unsigned long long pack_edge(float w) {
    return (1ULL << DEG_SHIFT) | (unsigned long long)(w * DEG_SCALE);
}
__device__ __forceinline__ float unpack_deg(unsigned long long v) {
    return (float)((double)(v & DEG_MASK) * (1.0 / (double)DEG_SCALE));
}
__device__ __forceinline__ int unpack_cnt(unsigned long long v) {
    return (int)(v >> DEG_SHIFT);
}
__device__ __forceinline__ float bf16_to_f(unsigned short u) {
    return __uint_as_float(((unsigned int)u) << 16);
}
__device__ __forceinline__ unsigned short f_to_bf16(float f) {
    unsigned int u = __float_as_uint(f);
    u += 0x7fffu + ((u >> 16) & 1u);   // round-to-nearest-even
    return (unsigned short)(u >> 16);
}

// ---------------- degree+count: one packed 64-bit atomic per edge, 4 edges/thread ----
__global__ void k_deg_cnt(const int4* __restrict__ col4, const float4* __restrict__ w4,
                          const int* __restrict__ col, const float* __restrict__ w,
                          unsigned long long* __restrict__ degcnt, int E4, int rem_base, int rem) {
    int t = blockIdx.x * 256 + threadIdx.x;
    if (t < E4) {
        int4   c = col4[t];
        float4 v = w4[t];
        atomicAdd(&degcnt[c.x], pack_edge(v.x));
        atomicAdd(&degcnt[c.y], pack_edge(v.y));
        atomicAdd(&degcnt[c.z], pack_edge(v.z));
        atomicAdd(&degcnt[c.w], pack_edge(v.w));
    }
    if (t < rem) {
        int e = rem_base + t;
        atomicAdd(&degcnt[col[e]], pack_edge(w[e]));
    }
}

// ------- scan phase 1 (also emits dinv = rsqrt(deg+1) from the packed word) --------
__global__ __launch_bounds__(1024) void k_scan1(const unsigned long long* __restrict__ degcnt,
                                                float* __restrict__ dinv,
                                                int* excl, int* partials, int n) {
    __shared__ int sm[1024];
    int gid = blockIdx.x * 1024 + threadIdx.x;
    int v = 0;
    if (gid < n) {
        unsigned long long dc = degcnt[gid];
        v = unpack_cnt(dc);
        dinv[gid] = rsqrtf(unpack_deg(dc) + 1.0f);
    }
    sm[threadIdx.x] = v;
    __syncthreads();
    for (int off = 1; off < 1024; off <<= 1) {
        int t = (threadIdx.x >= off) ? sm[threadIdx.x - off] : 0;
        __syncthreads();
        sm[threadIdx.x] += t;
        __syncthreads();
    }
    if (gid < n) excl[gid] = sm[threadIdx.x] - v;
    if (threadIdx.x == 1023) partials[blockIdx.x] = sm[1023];
}

__global__ void k_scan2(int* partials, int nb) {
    __shared__ int sm[128];
    int v = (threadIdx.x < nb) ? partials[threadIdx.x] : 0;
    sm[threadIdx.x] = v;
    __syncthreads();
    for (int off = 1; off < 128; off <<= 1) {
        int t = (threadIdx.x >= off) ? sm[threadIdx.x - off] : 0;
        __syncthreads();
        sm[threadIdx.x] += t;
        __syncthreads();
    }
    if (threadIdx.x < nb) partials[threadIdx.x] = sm[threadIdx.x] - v;
}

__global__ void k_scan3(int* excl, const int* partials, int* cur, int n, int total) {
    int gid = blockIdx.x * 256 + threadIdx.x;
    if (gid < n) {
        int v = excl[gid] + partials[gid >> 10];
        excl[gid] = v;
        cur[gid]  = v;
    } else if (gid == n) {
        excl[n] = total;
    }
}

// -------- CSR fill: 4 edges/thread (4 independent returning atomics in flight) -----
__global__ void k_fill(const int4* __restrict__ row4, const int4* __restrict__ col4,
                       const float4* __restrict__ w4,
                       const int* __restrict__ row, const int* __restrict__ col,
                       const float* __restrict__ w,
                       const float* __restrict__ dinv,
                       int* __restrict__ cur, float2* __restrict__ ep,
                       int E4, int rem_base, int rem) {
    int t = blockIdx.x * 256 + threadIdx.x;
    if (t < E4) {
        int4   r = row4[t];
        int4   c = col4[t];
        float4 v = w4[t];
        int s0 = atomicAdd(&cur[c.x], 1);
        int s1 = atomicAdd(&cur[c.y], 1);
        int s2 = atomicAdd(&cur[c.z], 1);
        int s3 = atomicAdd(&cur[c.w], 1);
        ep[s0] = make_float2(__int_as_float(r.x), dinv[r.x] * v.x * dinv[c.x]);
        ep[s1] = make_float2(__int_as_float(r.y), dinv[r.y] * v.y * dinv[c.y]);
        ep[s2] = make_float2(__int_as_float(r.z), dinv[r.z] * v.z * dinv[c.z]);
        ep[s3] = make_float2(__int_as_float(r.w), dinv[r.w] * v.w * dinv[c.w]);
    }
    if (t < rem) {
        int e = rem_base + t;
        int r = row[e], c = col[e];
        int slot = atomicAdd(&cur[c], 1);
        ep[slot] = make_float2(__int_as_float(r), dinv[r] * w[e] * dinv[c]);
    }
}

// ---------------- h1 = x @ W1, stored bf16 (wave per node, W1 in LDS) ----------------
__global__ void k_gemm1(const float* __restrict__ x, const float* __restrict__ W1,
                        unsigned short* __restrict__ h1b, int n) {
    __shared__ float Ws[64 * 64];
    for (int t = threadIdx.x; t < 4096; t += 256) Ws[t] = W1[t];
    __syncthreads();
    int lane = threadIdx.x & 63;
    int wave = threadIdx.x >> 6;
    for (int i = blockIdx.x * 4 + wave; i < n; i += gridDim.x * 4) {
        float xv = x[(size_t)i * 64 + lane];
        float acc = 0.f;
#pragma unroll
        for (int k = 0; k < 64; ++k) {
            float xk = __shfl(xv, k, 64);
            acc = fmaf(xk, Ws[k * 64 + lane], acc);
        }
        h1b[(size_t)i * 64 + lane] = f_to_bf16(acc);
    }
}

// ---- agg1 fused: bf16 gather-sum (4-way unrolled) + b1 + relu + dot(W2) -> h2[N] ----
__global__ void k_agg1(const unsigned short* __restrict__ h1b, const int* __restrict__ off,
                       const float2* __restrict__ ep, const float* __restrict__ dinv,
                       const float* __restrict__ b1, const float* __restrict__ W2,
                       float* __restrict__ h2, int n) {
    int lane = threadIdx.x & 63;
    int wave = threadIdx.x >> 6;
    int i = blockIdx.x * 4 + wave;
    if (i >= n) return;
    float di = dinv[i];
    float acc = bf16_to_f(h1b[(size_t)i * 64 + lane]) * (di * di);   // self-loop
    int s0 = off[i], s1 = off[i + 1];
    int s = s0;
    for (; s + 4 <= s1; s += 4) {
        float2 e0 = ep[s], e1 = ep[s + 1], e2 = ep[s + 2], e3 = ep[s + 3];
        float v0 = bf16_to_f(h1b[(size_t)__float_as_int(e0.x) * 64 + lane]);
        float v1 = bf16_to_f(h1b[(size_t)__float_as_int(e1.x) * 64 + lane]);
        float v2 = bf16_to_f(h1b[(size_t)__float_as_int(e2.x) * 64 + lane]);
        float v3 = bf16_to_f(h1b[(size_t)__float_as_int(e3.x) * 64 + lane]);
        acc = fmaf(v0, e0.y, acc);
        acc = fmaf(v1, e1.y, acc);
        acc = fmaf(v2, e2.y, acc);
        acc = fmaf(v3, e3.y, acc);
    }
    for (; s < s1; ++s) {
        float2 e = ep[s];
        acc = fmaf(bf16_to_f(h1b[(size_t)__float_as_int(e.x) * 64 + lane]), e.y, acc);
    }
    float v = fmaxf(acc + b1[lane], 0.f);
    float p = v * W2[lane];
#pragma unroll
    for (int o = 32; o > 0; o >>= 1) p += __shfl_down(p, o, 64);
    if (lane == 0) h2[i] = p;
}

// ---------------- agg2 on scalars (4-way unrolled) + b2 -> out[N] ----------------
__global__ void k_agg2(const float* __restrict__ h2, const int* __restrict__ off,
                       const float2* __restrict__ ep, const float* __restrict__ dinv,
                       const float* __restrict__ b2, float* __restrict__ out, int n) {
    int i = blockIdx.x * 256 + threadIdx.x;
    if (i >= n) return;
    float di = dinv[i];
    float acc = h2[i] * di * di;       // self-loop
    int s0 = off[i], s1 = off[i + 1];
    int s = s0;
    for (; s + 4 <= s1; s += 4) {
        float2 e0 = ep[s], e1 = ep[s + 1], e2 = ep[s + 2], e3 = ep[s + 3];
        float v0 = h2[__float_as_int(e0.x)];
        float v1 = h2[__float_as_int(e1.x)];
        float v2 = h2[__float_as_int(e2.x)];
        float v3 = h2[__float_as_int(e3.x)];
        acc = fmaf(v0, e0.y, acc);
        acc = fmaf(v1, e1.y, acc);
        acc = fmaf(v2, e2.y, acc);
        acc = fmaf(v3, e3.y, acc);
    }
    for (; s < s1; ++s) {
        float2 e = ep[s];
        acc = fmaf(h2[__float_as_int(e.x)], e.y, acc);
    }
    out[i] = acc + b2[0];
}

extern "C" void kernel_launch(void* const* d_in, const int* in_sizes, int n_in,
                              void* d_out, int out_size, void* d_ws, size_t ws_size,
                              hipStream_t stream) {
    const float* x  = (const float*)d_in[0];
    const int*   ei = (const int*)d_in[1];
    const float* w  = (const float*)d_in[2];
    const float* W1 = (const float*)d_in[3];
    const float* b1 = (const float*)d_in[4];
    const float* W2 = (const float*)d_in[5];
    const float* b2 = (const float*)d_in[6];
    float* out = (float*)d_out;

    const int N = in_sizes[0] / 64;
    const int E = in_sizes[2];
    const int* row = ei;
    const int* col = ei + E;

    // workspace carve-up (~26 MB)
    char* p = (char*)d_ws;
    unsigned long long* degcnt = (unsigned long long*)p; p += (size_t)N * 8;
    float*  dinv = (float*)p;   p += (size_t)N * 4;
    int*    off  = (int*)p;     p += (size_t)(N + 1) * 4;
    int*    cur  = (int*)p;     p += (size_t)N * 4;
    int*    parts= (int*)p;     p += 1024;
    float2* ep   = (float2*)p;  p += (size_t)E * 8;
    unsigned short* h1b = (unsigned short*)p; p += (size_t)N * 64 * 2;
    float*  h2   = (float*)p;   p += (size_t)N * 4;

    const int E4       = E / 4;
    const int rem_base = E4 * 4;
    const int rem      = E - rem_base;
    const int gE4 = (E4 + 255) / 256;
    const int gN  = (N + 255) / 256;
    const int nb1 = (N + 1023) / 1024;
    const int gN1 = (N + 1 + 255) / 256;

    (void)hipMemsetAsync(degcnt, 0, (size_t)N * 8, stream);
    k_deg_cnt<<<gE4, 256, 0, stream>>>((const int4*)col, (const float4*)w, col, w,
                                       degcnt, E4, rem_base, rem);
    k_scan1<<<nb1, 1024, 0, stream>>>(degcnt, dinv, off, parts, N);
    k_scan2<<<1, 128, 0, stream>>>(parts, nb1);
    k_scan3<<<gN1, 256, 0, stream>>>(off, parts, cur, N, E);
    k_fill<<<gE4, 256, 0, stream>>>((const int4*)row, (const int4*)col, (const float4*)w,
                                    row, col, w, dinv, cur, ep, E4, rem_base, rem);
    k_gemm1<<<1024, 256, 0, stream>>>(x, W1, h1b, N);
    k_agg1<<<(N + 3) / 4, 256, 0, stream>>>(h1b, off, ep, dinv, b1, W2, h2, N);
    k_agg2<<<gN, 256, 0, stream>>>(h2, off, ep, dinv, b2, out, N);
}

// Round 5
// 310.716 us; speedup vs baseline: 1.5781x; 1.2480x over previous
//
#include <hip/hip_runtime.h>

// degcnt[i] packed u64: high 20 bits = count, low 44 bits = sum(w)*2^32 fixed point
#define DEG_SHIFT 44
#define DEG_MASK  ((1ULL << DEG_SHIFT) - 1)
#define DEG_SCALE 4294967296.0f   // 2^32

__device__ __forceinline__ unsigned long long pack_edge(float w) {
    return (1ULL << DEG_SHIFT) | (unsigned long long)(w * DEG_SCALE);
}
__device__ __forceinline__ float unpack_deg(unsigned long long v) {
    return (float)((double)(v & DEG_MASK) * (1.0 / (double)DEG_SCALE));
}
__device__ __forceinline__ float bf16_to_f(unsigned short u) {
    return __uint_as_float(((unsigned int)u) << 16);
}
__device__ __forceinline__ unsigned short f_to_bf16(float f) {
    unsigned int u = __float_as_uint(f);
    u += 0x7fffu + ((u >> 16) & 1u);   // round-to-nearest-even
    return (unsigned short)(u >> 16);
}
// ep word: [31:15] = src (17b), [14:0] = bf16(norm) sans sign (norm >= 0)
__device__ __forceinline__ unsigned int pack_ep(int src, float nm) {
    return ((unsigned int)src << 15) | (unsigned int)(f_to_bf16(nm) & 0x7fff);
}
__device__ __forceinline__ float ep_norm(unsigned int e) {
    return __uint_as_float((e & 0x7fffu) << 16);
}

// ---- fused: [0,nDeg) blocks = degree+count+rank; [nDeg,nDeg+nGemm) = h1 = x@W1 ----
__global__ void k_pre(const int4* __restrict__ col4, const float4* __restrict__ w4,
                      const int* __restrict__ col, const float* __restrict__ w,
                      unsigned long long* __restrict__ degcnt, unsigned short* __restrict__ rank,
                      const float* __restrict__ x, const float* __restrict__ W1,
                      unsigned short* __restrict__ h1b,
                      int E4, int rem_base, int rem, int nDeg, int nGemm, int n) {
    __shared__ float Ws[64 * 64];
    if ((int)blockIdx.x < nDeg) {
        int t = blockIdx.x * 256 + threadIdx.x;
        if (t < E4) {
            int4   c = col4[t];
            float4 v = w4[t];
            unsigned long long o0 = atomicAdd(&degcnt[c.x], pack_edge(v.x));
            unsigned long long o1 = atomicAdd(&degcnt[c.y], pack_edge(v.y));
            unsigned long long o2 = atomicAdd(&degcnt[c.z], pack_edge(v.z));
            unsigned long long o3 = atomicAdd(&degcnt[c.w], pack_edge(v.w));
            ushort4 r4;
            r4.x = (unsigned short)(o0 >> DEG_SHIFT);
            r4.y = (unsigned short)(o1 >> DEG_SHIFT);
            r4.z = (unsigned short)(o2 >> DEG_SHIFT);
            r4.w = (unsigned short)(o3 >> DEG_SHIFT);
            *(ushort4*)(rank + 4 * (size_t)t) = r4;
        }
        if (t < rem) {
            int e = rem_base + t;
            unsigned long long o = atomicAdd(&degcnt[col[e]], pack_edge(w[e]));
            rank[e] = (unsigned short)(o >> DEG_SHIFT);
        }
    } else {
        int b = blockIdx.x - nDeg;
        for (int t = threadIdx.x; t < 4096; t += 256) Ws[t] = W1[t];
        __syncthreads();
        int lane = threadIdx.x & 63;
        int wave = threadIdx.x >> 6;
        for (int i = b * 4 + wave; i < n; i += nGemm * 4) {
            float xv = x[(size_t)i * 64 + lane];
            float acc = 0.f;
#pragma unroll
            for (int k = 0; k < 64; ++k) {
                float xk = __shfl(xv, k, 64);
                acc = fmaf(xk, Ws[k * 64 + lane], acc);
            }
            h1b[(size_t)i * 64 + lane] = f_to_bf16(acc);
        }
    }
}

// ------- scan phase 1 (also emits dinv = rsqrt(deg+1)) --------
__global__ __launch_bounds__(1024) void k_scan1(const unsigned long long* __restrict__ degcnt,
                                                float* __restrict__ dinv,
                                                int* excl, int* partials, int n) {
    __shared__ int sm[1024];
    int gid = blockIdx.x * 1024 + threadIdx.x;
    int v = 0;
    if (gid < n) {
        unsigned long long dc = degcnt[gid];
        v = (int)(dc >> DEG_SHIFT);
        dinv[gid] = rsqrtf(unpack_deg(dc) + 1.0f);
    }
    sm[threadIdx.x] = v;
    __syncthreads();
    for (int off = 1; off < 1024; off <<= 1) {
        int t = (threadIdx.x >= off) ? sm[threadIdx.x - off] : 0;
        __syncthreads();
        sm[threadIdx.x] += t;
        __syncthreads();
    }
    if (gid < n) excl[gid] = sm[threadIdx.x] - v;
    if (threadIdx.x == 1023) partials[blockIdx.x] = sm[1023];
}

__global__ void k_scan2(int* partials, int nb) {
    __shared__ int sm[128];
    int v = (threadIdx.x < nb) ? partials[threadIdx.x] : 0;
    sm[threadIdx.x] = v;
    __syncthreads();
    for (int off = 1; off < 128; off <<= 1) {
        int t = (threadIdx.x >= off) ? sm[threadIdx.x - off] : 0;
        __syncthreads();
        sm[threadIdx.x] += t;
        __syncthreads();
    }
    if (threadIdx.x < nb) partials[threadIdx.x] = sm[threadIdx.x] - v;
}

__global__ void k_scan3(int* excl, const int* partials, int n, int total) {
    int gid = blockIdx.x * 256 + threadIdx.x;
    if (gid < n) {
        excl[gid] += partials[gid >> 10];
    } else if (gid == n) {
        excl[n] = total;
    }
}

// -------- CSR fill, atomic-free: slot = off[col] + rank[e]; 4B packed store --------
__global__ void k_fill(const int4* __restrict__ row4, const int4* __restrict__ col4,
                       const float4* __restrict__ w4,
                       const int* __restrict__ row, const int* __restrict__ col,
                       const float* __restrict__ w,
                       const unsigned short* __restrict__ rank,
                       const int* __restrict__ off, const float* __restrict__ dinv,
                       unsigned int* __restrict__ ep,
                       int E4, int rem_base, int rem) {
    int t = blockIdx.x * 256 + threadIdx.x;
    if (t < E4) {
        int4   r = row4[t];
        int4   c = col4[t];
        float4 v = w4[t];
        ushort4 k4 = *(const ushort4*)(rank + 4 * (size_t)t);
        int s0 = off[c.x] + k4.x;
        int s1 = off[c.y] + k4.y;
        int s2 = off[c.z] + k4.z;
        int s3 = off[c.w] + k4.w;
        ep[s0] = pack_ep(r.x, dinv[r.x] * v.x * dinv[c.x]);
        ep[s1] = pack_ep(r.y, dinv[r.y] * v.y * dinv[c.y]);
        ep[s2] = pack_ep(r.z, dinv[r.z] * v.z * dinv[c.z]);
        ep[s3] = pack_ep(r.w, dinv[r.w] * v.w * dinv[c.w]);
    }
    if (t < rem) {
        int e = rem_base + t;
        int r = row[e], c = col[e];
        ep[off[c] + rank[e]] = pack_ep(r, dinv[r] * w[e] * dinv[c]);
    }
}

// ---- agg1 fused: bf16 gather-sum (4-way unrolled) + b1 + relu + dot(W2) -> h2[N] ----
__global__ void k_agg1(const unsigned short* __restrict__ h1b, const int* __restrict__ off,
                       const unsigned int* __restrict__ ep, const float* __restrict__ dinv,
                       const float* __restrict__ b1, const float* __restrict__ W2,
                       float* __restrict__ h2, int n) {
    int lane = threadIdx.x & 63;
    int wave = threadIdx.x >> 6;
    int i = blockIdx.x * 4 + wave;
    if (i >= n) return;
    float di = dinv[i];
    float acc = bf16_to_f(h1b[(size_t)i * 64 + lane]) * (di * di);   // self-loop
    int s0 = off[i], s1 = off[i + 1];
    int s = s0;
    for (; s + 4 <= s1; s += 4) {
        unsigned int e0 = ep[s], e1 = ep[s + 1], e2 = ep[s + 2], e3 = ep[s + 3];
        float v0 = bf16_to_f(h1b[(size_t)(e0 >> 15) * 64 + lane]);
        float v1 = bf16_to_f(h1b[(size_t)(e1 >> 15) * 64 + lane]);
        float v2 = bf16_to_f(h1b[(size_t)(e2 >> 15) * 64 + lane]);
        float v3 = bf16_to_f(h1b[(size_t)(e3 >> 15) * 64 + lane]);
        acc = fmaf(v0, ep_norm(e0), acc);
        acc = fmaf(v1, ep_norm(e1), acc);
        acc = fmaf(v2, ep_norm(e2), acc);
        acc = fmaf(v3, ep_norm(e3), acc);
    }
    for (; s < s1; ++s) {
        unsigned int e = ep[s];
        acc = fmaf(bf16_to_f(h1b[(size_t)(e >> 15) * 64 + lane]), ep_norm(e), acc);
    }
    float v = fmaxf(acc + b1[lane], 0.f);
    float p = v * W2[lane];
#pragma unroll
    for (int o = 32; o > 0; o >>= 1) p += __shfl_down(p, o, 64);
    if (lane == 0) h2[i] = p;
}

// ---------------- agg2 on scalars (4-way unrolled) + b2 -> out[N] ----------------
__global__ void k_agg2(const float* __restrict__ h2, const int* __restrict__ off,
                       const unsigned int* __restrict__ ep, const float* __restrict__ dinv,
                       const float* __restrict__ b2, float* __restrict__ out, int n) {
    int i = blockIdx.x * 256 + threadIdx.x;
    if (i >= n) return;
    float di = dinv[i];
    float acc = h2[i] * di * di;       // self-loop
    int s0 = off[i], s1 = off[i + 1];
    int s = s0;
    for (; s + 4 <= s1; s += 4) {
        unsigned int e0 = ep[s], e1 = ep[s + 1], e2 = ep[s + 2], e3 = ep[s + 3];
        float v0 = h2[e0 >> 15];
        float v1 = h2[e1 >> 15];
        float v2 = h2[e2 >> 15];
        float v3 = h2[e3 >> 15];
        acc = fmaf(v0, ep_norm(e0), acc);
        acc = fmaf(v1, ep_norm(e1), acc);
        acc = fmaf(v2, ep_norm(e2), acc);
        acc = fmaf(v3, ep_norm(e3), acc);
    }
    for (; s < s1; ++s) {
        unsigned int e = ep[s];
        acc = fmaf(h2[e >> 15], ep_norm(e), acc);
    }
    out[i] = acc + b2[0];
}

extern "C" void kernel_launch(void* const* d_in, const int* in_sizes, int n_in,
                              void* d_out, int out_size, void* d_ws, size_t ws_size,
                              hipStream_t stream) {
    const float* x  = (const float*)d_in[0];
    const int*   ei = (const int*)d_in[1];
    const float* w  = (const float*)d_in[2];
    const float* W1 = (const float*)d_in[3];
    const float* b1 = (const float*)d_in[4];
    const float* W2 = (const float*)d_in[5];
    const float* b2 = (const float*)d_in[6];
    float* out = (float*)d_out;

    const int N = in_sizes[0] / 64;
    const int E = in_sizes[2];
    const int* row = ei;
    const int* col = ei + E;

    // workspace carve-up (~23 MB); keep 8B-aligned chunks first
    char* p = (char*)d_ws;
    unsigned long long* degcnt = (unsigned long long*)p; p += (size_t)N * 8;
    unsigned short* rank = (unsigned short*)p; p += (size_t)E * 2;       // 8B-aligned
    unsigned short* h1b  = (unsigned short*)p; p += (size_t)N * 64 * 2;
    float*  dinv = (float*)p;   p += (size_t)N * 4;
    int*    off  = (int*)p;     p += (size_t)(N + 2) * 4;
    int*    parts= (int*)p;     p += 1024;
    unsigned int* ep = (unsigned int*)p; p += (size_t)E * 4;
    float*  h2   = (float*)p;   p += (size_t)N * 4;

    const int E4       = E / 4;
    const int rem_base = E4 * 4;
    const int rem      = E - rem_base;
    const int nDeg  = (max(E4, rem) + 255) / 256;
    const int nGemm = 1024;
    const int gN  = (N + 255) / 256;
    const int nb1 = (N + 1023) / 1024;
    const int gN1 = (N + 1 + 255) / 256;

    (void)hipMemsetAsync(degcnt, 0, (size_t)N * 8, stream);
    k_pre<<<nDeg + nGemm, 256, 0, stream>>>((const int4*)col, (const float4*)w, col, w,
                                            degcnt, rank, x, W1, h1b,
                                            E4, rem_base, rem, nDeg, nGemm, N);
    k_scan1<<<nb1, 1024, 0, stream>>>(degcnt, dinv, off, parts, N);
    k_scan2<<<1, 128, 0, stream>>>(parts, nb1);
    k_scan3<<<gN1, 256, 0, stream>>>(off, parts, N, E);
    k_fill<<<nDeg, 256, 0, stream>>>((const int4*)row, (const int4*)col, (const float4*)w,
                                     row, col, w, rank, off, dinv, ep, E4, rem_base, rem);
    k_agg1<<<(N + 3) / 4, 256, 0, stream>>>(h1b, off, ep, dinv, b1, W2, h2, N);
    k_agg2<<<gN, 256, 0, stream>>>(h2, off, ep, dinv, b2, out, N);
}